// Round 7
// baseline (360.225 us; speedup 1.0000x reference)
//
#include <hip/hip_runtime.h>
#include <hip/hip_bf16.h>
#include <cstdint>
#include <cstddef>
#include <math.h>

#define NN 50000
#define NE 800000
#define INC 512
#define HIDC 256
#define NBLK ((NN + 255) / 256)

typedef __attribute__((ext_vector_type(8))) short s8v;   // 8 bf16 = 4 VGPR
typedef __attribute__((ext_vector_type(4))) float f4v;
typedef unsigned int u32;

#define VMC(n)  asm volatile("s_waitcnt vmcnt(" #n ")" ::: "memory")
#define LGKM0   asm volatile("s_waitcnt lgkmcnt(0)" ::: "memory")
#define BAR()   do { __builtin_amdgcn_s_barrier(); asm volatile("" ::: "memory"); } while (0)

__device__ __forceinline__ float b2f(unsigned short u) {
    return __uint_as_float(((unsigned)u) << 16);
}
__device__ __forceinline__ unsigned short f2b(float f) {
    __hip_bfloat16 h = __float2bfloat16(f);
    return *reinterpret_cast<unsigned short*>(&h);
}
// async 16B global->LDS (dest = wave-uniform base, HW adds lane*16; src is per-lane)
__device__ __forceinline__ void gload16(const void* g, void* l) {
    __builtin_amdgcn_global_load_lds(
        (const __attribute__((address_space(1))) u32*)g,
        (__attribute__((address_space(3))) u32*)l, 16, 0, 0);
}

// ---------------- CSR build ----------------
__global__ void k_deg_count(const int* __restrict__ dst, int* __restrict__ cnt, int e) {
    int i = blockIdx.x * 256 + threadIdx.x;
    if (i < e) atomicAdd(&cnt[dst[i]], 1);
}
__global__ void k_scan1(const int* __restrict__ cnt, int* __restrict__ excl,
                        int* __restrict__ bsum, float* __restrict__ dinv, int n) {
    __shared__ int s[256];
    int i = blockIdx.x * 256 + threadIdx.x;
    int v = (i < n) ? cnt[i] : 0;
    if (i < n) dinv[i] = rsqrtf((float)v + 1.0f);
    s[threadIdx.x] = v;
    __syncthreads();
    for (int off = 1; off < 256; off <<= 1) {
        int t = (threadIdx.x >= off) ? s[threadIdx.x - off] : 0;
        __syncthreads();
        s[threadIdx.x] += t;
        __syncthreads();
    }
    if (i < n) excl[i] = s[threadIdx.x] - v;
    if (threadIdx.x == 255) bsum[blockIdx.x] = s[255];
}
__global__ void k_scan2(int* __restrict__ bsum, int* __restrict__ bsumx, int nb) {
    __shared__ int s[256];
    int t = threadIdx.x;
    int v = (t < nb) ? bsum[t] : 0;
    s[t] = v;
    __syncthreads();
    for (int off = 1; off < 256; off <<= 1) {
        int tt = (t >= off) ? s[t - off] : 0;
        __syncthreads();
        s[t] += tt;
        __syncthreads();
    }
    if (t < nb) bsumx[t] = s[t] - v;
}
__global__ void k_scan3(int* __restrict__ rowptr, const int* __restrict__ bsumx, int n, int e) {
    int i = blockIdx.x * 256 + threadIdx.x;
    if (i < n) rowptr[i] += bsumx[blockIdx.x];
    if (i == 0) rowptr[n] = e;
}
__global__ void k_fill(const int* __restrict__ src, const int* __restrict__ dst,
                       const int* __restrict__ rowptr, int* __restrict__ cursor,
                       int* __restrict__ col, int e) {
    int i = blockIdx.x * 256 + threadIdx.x;
    if (i >= e) return;
    int d = dst[i];
    int pos = rowptr[d] + atomicAdd(&cursor[d], 1);
    col[pos] = src[i];
}

// ---------------- transposes for coalesced fold ----------------
__global__ void k_tr2(const float* __restrict__ Wg3, const float* __restrict__ Wc3,
                      float* __restrict__ Wg3t, float* __restrict__ Wc3t) {
    int t = blockIdx.x * 256 + threadIdx.x;
    if (t < 256 * 350) { int k = t / 350, i = t - k * 350; Wg3t[i * 256 + k] = Wg3[t]; }
    if (t < 350 * 350) { int i = t / 350, j = t - i * 350; Wc3t[j * 350 + i] = Wc3[t]; }
}

// ---------------- fused weight prep ----------------
// blocks 0..511: W1t_sw (XOR 8-group, k-blocked) ; 512..959: Wftp col j = b-512
// (plain k-blocked [kb][448][32]) ; 960..961: bfv
__global__ void k_prep(const float* __restrict__ W1,
                       const float* __restrict__ Wg0, const float* __restrict__ Wc0,
                       const float* __restrict__ bg0, const float* __restrict__ bc0,
                       const float* __restrict__ Wg1, const float* __restrict__ Wc1,
                       const float* __restrict__ bg1, const float* __restrict__ bc1,
                       const float* __restrict__ Wg2, const float* __restrict__ Wc2,
                       const float* __restrict__ bg2, const float* __restrict__ bc2,
                       const float* __restrict__ Wg3, const float* __restrict__ Wc3,
                       const float* __restrict__ bg3, const float* __restrict__ bc3,
                       const float* __restrict__ Wg3t, const float* __restrict__ Wc3t,
                       unsigned short* __restrict__ W1t_sw, unsigned short* __restrict__ Wftp,
                       float* __restrict__ bfv)
{
    __shared__ float Wcj[352];
    int b = blockIdx.x, tid = threadIdx.x;
    if (b < 512) {
        int t = b * 256 + tid;            // 256*512 elems
        int c = t >> 9, k = t & 511;
        int chs = ((k >> 3) & 7) ^ (c & 7);
        W1t_sw[(size_t)(k >> 6) * 16384 + c * 64 + chs * 8 + (k & 7)] = f2b(W1[(size_t)k * 256 + c]);
    } else if (b < 960) {
        int j = b - 512, k = tid;
        float s = 0.f;
        if (j < 350) {
            for (int i = tid; i < 350; i += 256) Wcj[i] = Wc3t[(size_t)j * 350 + i];
            __syncthreads();
            for (int i = 0; i < 350; ++i) s += Wg3t[i * 256 + k] * Wcj[i];
        } else if (j >= 352 && j < 362) {
            int jj = j - 352; for (int i = 0; i < 10; ++i) s += Wg0[k * 10 + i] * Wc0[i * 10 + jj];
        } else if (j >= 362 && j < 387) {
            int jj = j - 362; for (int i = 0; i < 25; ++i) s += Wg1[k * 25 + i] * Wc1[i * 25 + jj];
        } else if (j >= 387 && j < 403) {
            int jj = j - 387; for (int i = 0; i < 16; ++i) s += Wg2[k * 16 + i] * Wc2[i * 16 + jj];
        }
        Wftp[((size_t)(k >> 5) * 448 + j) * 32 + (k & 31)] = f2b(s);
    } else {
        int j = (b - 960) * 256 + tid;
        if (j >= 448) return;
        float s = 0.f;
        if (j < 350)                  { s = bc3[j]; for (int i = 0; i < 350; ++i) s += bg3[i] * Wc3[(size_t)i * 350 + j]; }
        else if (j >= 352 && j < 362) { int jj = j - 352; s = bc0[jj]; for (int i = 0; i < 10; ++i) s += bg0[i] * Wc0[i * 10 + jj]; }
        else if (j >= 362 && j < 387) { int jj = j - 362; s = bc1[jj]; for (int i = 0; i < 25; ++i) s += bg1[i] * Wc1[i * 25 + jj]; }
        else if (j >= 387 && j < 403) { int jj = j - 387; s = bc2[jj]; for (int i = 0; i < 16; ++i) s += bg2[i] * Wc2[i * 16 + jj]; }
        bfv[j] = s;
    }
}

// ---------------- gemm1: xwb = bf16( fp32 X[M][512] @ W1 ) ----------------
// BM=64, BN=256, BK=64, 256 thr = 4 waves (2M x 2N), wave-tile 32x128
// double-buffered, counted vmcnt: B via 8 DMAs/wave, A via 4 reg-loads/thread.
__global__ __launch_bounds__(256, 2) void gemm1_conv(
    const float* __restrict__ X, const unsigned short* __restrict__ Bsw,
    unsigned short* __restrict__ C, int M)
{
    __shared__ s8v lds[5120];   // A0 @0 (512) | A1 @512 | B0 @1024 (2048) | B1 @3072
    const int t = threadIdx.x;
    const int lane = t & 63, wv = t >> 6;
    const int wvM = wv >> 1, wvN = wv & 1;
    const int l15 = lane & 15, lq = lane >> 4;
    const int row0 = blockIdx.x * 64;

    const int arow = t >> 2, q = t & 3;
    int gr = row0 + arow; if (gr >= M) gr = M - 1;
    const float* asrc = X + (size_t)gr * INC + q * 16;
    const int awp0 = arow * 8 + ((q * 2) ^ (arow & 7));
    const int awp1 = arow * 8 + ((q * 2 + 1) ^ (arow & 7));

    float4 fa0, fa1, fa2, fa3;
#define STAGE_B1(kbn, buf) do { \
    const unsigned short* bs_ = Bsw + (size_t)(kbn) * 2048 * 8; \
    int bb_ = 1024 + (buf) * 2048; \
    _Pragma("unroll") \
    for (int sB = 0; sB < 8; ++sB) { \
        int g_ = (wv * 8 + sB) * 64; \
        gload16(bs_ + (size_t)(g_ + lane) * 8, (void*)&lds[bb_ + g_]); \
    } } while (0)
#define LOAD_A1(kbn) do { \
    fa0 = *(const float4*)(asrc + (kbn) * 64); \
    fa1 = *(const float4*)(asrc + (kbn) * 64 + 4); \
    fa2 = *(const float4*)(asrc + (kbn) * 64 + 8); \
    fa3 = *(const float4*)(asrc + (kbn) * 64 + 12); } while (0)

    f4v acc[2][8] = {};
    STAGE_B1(0, 0);
    LOAD_A1(0);
    for (int kb = 0; kb < 8; ++kb) {
        const int cur = kb & 1, nxt = cur ^ 1;
        if (kb < 7) STAGE_B1(kb + 1, nxt);
        if (kb < 7) { VMC(8); } else { VMC(0); }
        // convert A(kb) regs -> ds_write into bufA[cur]
        s8v o0, o1;
        o0[0]=(short)f2b(fa0.x); o0[1]=(short)f2b(fa0.y); o0[2]=(short)f2b(fa0.z); o0[3]=(short)f2b(fa0.w);
        o0[4]=(short)f2b(fa1.x); o0[5]=(short)f2b(fa1.y); o0[6]=(short)f2b(fa1.z); o0[7]=(short)f2b(fa1.w);
        o1[0]=(short)f2b(fa2.x); o1[1]=(short)f2b(fa2.y); o1[2]=(short)f2b(fa2.z); o1[3]=(short)f2b(fa2.w);
        o1[4]=(short)f2b(fa3.x); o1[5]=(short)f2b(fa3.y); o1[6]=(short)f2b(fa3.z); o1[7]=(short)f2b(fa3.w);
        lds[cur * 512 + awp0] = o0;
        lds[cur * 512 + awp1] = o1;
        if (kb < 7) LOAD_A1(kb + 1);
        LGKM0; BAR();
        const int ab = cur * 512, bb = 1024 + cur * 2048;
#pragma unroll
        for (int kk = 0; kk < 2; ++kk) {
            const int chr = (kk * 4 + lq) ^ (l15 & 7);
            s8v a0 = lds[ab + (wvM * 32 + l15) * 8 + chr];
            s8v a1 = lds[ab + (wvM * 32 + 16 + l15) * 8 + chr];
#pragma unroll
            for (int cf = 0; cf < 8; ++cf) {
                s8v bf = lds[bb + (wvN * 128 + cf * 16 + l15) * 8 + chr];
                acc[0][cf] = __builtin_amdgcn_mfma_f32_16x16x32_bf16(a0, bf, acc[0][cf], 0, 0, 0);
                acc[1][cf] = __builtin_amdgcn_mfma_f32_16x16x32_bf16(a1, bf, acc[1][cf], 0, 0, 0);
            }
        }
        LGKM0; BAR();
    }
#pragma unroll
    for (int rf = 0; rf < 2; ++rf)
#pragma unroll
    for (int r = 0; r < 4; ++r) {
        int row = row0 + wvM * 32 + rf * 16 + lq * 4 + r;
        if (row >= M) continue;
#pragma unroll
        for (int cf = 0; cf < 8; ++cf)
            C[(size_t)row * HIDC + wvN * 128 + cf * 16 + l15] = f2b(acc[rf][cf][r]);
    }
#undef STAGE_B1
#undef LOAD_A1
}

// ---------------- gather: 2 nodes/wave, 32 lanes x ushort8 per row ----------------
template <bool RELU, bool BIAS>
__global__ __launch_bounds__(256) void k_gather2(
    const unsigned short* __restrict__ feat, const int* __restrict__ rowptr,
    const int* __restrict__ col, const float* __restrict__ dinv,
    const float* __restrict__ bias, unsigned short* __restrict__ out, int n)
{
    int unit = (blockIdx.x * 256 + threadIdx.x) >> 5;
    int l32 = threadIdx.x & 31;
    if (unit >= n) return;
    float di = dinv[unit];
    int p0 = rowptr[unit], p1 = rowptr[unit + 1];
    int deg = p1 - p0;
    int myc = 0; float mydj = 0.f;
    if (l32 < deg) { myc = col[p0 + l32]; mydj = dinv[myc]; }
    float acc[8] = {};
    int dmin = deg < 32 ? deg : 32;
    int base = threadIdx.x & 32;
#pragma unroll 2
    for (int q = 0; q < dmin; ++q) {
        int j = __shfl(myc, base + q);
        float dj = __shfl(mydj, base + q);
        s8v v = *(const s8v*)(feat + (size_t)j * HIDC + l32 * 8);
#pragma unroll
        for (int c = 0; c < 8; ++c) acc[c] += dj * b2f((unsigned short)v[c]);
    }
    for (int p = p0 + 32; p < p1; ++p) {
        int j = col[p];
        float dj = dinv[j];
        s8v v = *(const s8v*)(feat + (size_t)j * HIDC + l32 * 8);
#pragma unroll
        for (int c = 0; c < 8; ++c) acc[c] += dj * b2f((unsigned short)v[c]);
    }
    s8v sv = *(const s8v*)(feat + (size_t)unit * HIDC + l32 * 8);
    float dd = di * di;
    s8v o;
#pragma unroll
    for (int c = 0; c < 8; ++c) {
        float r = di * acc[c] + dd * b2f((unsigned short)sv[c]);
        if (BIAS) r += bias[l32 * 8 + c];
        if (RELU) r = fmaxf(r, 0.f);
        o[c] = (short)f2b(r);
    }
    *(s8v*)(out + (size_t)unit * HIDC + l32 * 8) = o;
}

// ---------------- gemm2 + 4-head softmax ----------------
// BM=64, BN=448, BK=32 (linear chunks), 512 thr = 8 waves (2M x 4N), wave-tile 32x112
// double-buffered A(4KB)+B(28KB): 64KB total -> 2 blocks/CU; vmcnt(4)/wave/k-step.
__global__ __launch_bounds__(512, 4) void gemm2_heads(
    const unsigned short* __restrict__ Ap, const unsigned short* __restrict__ Bp,
    const float* __restrict__ bfv,
    float* __restrict__ o0, float* __restrict__ o1,
    float* __restrict__ o2, float* __restrict__ o3, int M)
{
    __shared__ s8v lds[4096];   // A0 @0 (256) | A1 @256 | B0 @512 (1792) | B1 @2304
    const int t = threadIdx.x;
    const int lane = t & 63, wv = t >> 6;
    const int wvM = wv >> 2, wvN = wv & 3;
    const int l15 = lane & 15, lq = lane >> 4;
    const int row0 = blockIdx.x * 64;

#define STAGE2(kbn, buf) do { \
    if (wv == 0) { \
        _Pragma("unroll") \
        for (int s = 0; s < 4; ++s) { \
            int ci_ = s * 64 + lane; \
            int row_ = ci_ >> 2, ch_ = ci_ & 3; \
            int grow_ = row0 + row_; if (grow_ >= M) grow_ = M - 1; \
            gload16(Ap + (size_t)grow_ * HIDC + (kbn) * 32 + ch_ * 8, \
                    (void*)&lds[(buf) * 256 + s * 64]); \
        } \
    } else { \
        _Pragma("unroll") \
        for (int s = 0; s < 4; ++s) { \
            int bg_ = (wv - 1) * 4 + s; \
            int bci_ = bg_ * 64 + lane; \
            int j_ = bci_ >> 2, ch_ = bci_ & 3; \
            gload16(Bp + ((size_t)(kbn) * 448 + j_) * 32 + ch_ * 8, \
                    (void*)&lds[512 + (buf) * 1792 + bg_ * 64]); \
        } \
    } } while (0)

    f4v acc[2][7] = {};
    STAGE2(0, 0);
    for (int kb = 0; kb < 8; ++kb) {
        const int cur = kb & 1, nxt = cur ^ 1;
        if (kb < 7) STAGE2(kb + 1, nxt);
        if (kb < 7) { VMC(4); } else { VMC(0); }
        LGKM0; BAR();
        const int ab = cur * 256, bb = 512 + cur * 1792;
        s8v a0 = lds[ab + (wvM * 32 + l15) * 4 + lq];
        s8v a1 = lds[ab + (wvM * 32 + 16 + l15) * 4 + lq];
#pragma unroll
        for (int cf = 0; cf < 7; ++cf) {
            s8v bf = lds[bb + (wvN * 112 + cf * 16 + l15) * 4 + lq];
            acc[0][cf] = __builtin_amdgcn_mfma_f32_16x16x32_bf16(a0, bf, acc[0][cf], 0, 0, 0);
            acc[1][cf] = __builtin_amdgcn_mfma_f32_16x16x32_bf16(a1, bf, acc[1][cf], 0, 0, 0);
        }
        LGKM0; BAR();
    }
#undef STAGE2
    // ---- epilogue: bias + 4-head segmented softmax ----
    float* smx = (float*)lds;   // reuse: amax[64][4]@0, asum@256, hmax@512, hsum@704
#pragma unroll
    for (int cf = 0; cf < 7; ++cf) {
        float bb = bfv[wvN * 112 + cf * 16 + l15];
#pragma unroll
        for (int rf = 0; rf < 2; ++rf)
#pragma unroll
        for (int r = 0; r < 4; ++r) acc[rf][cf][r] += bb;
    }
#pragma unroll
    for (int rf = 0; rf < 2; ++rf)
#pragma unroll
    for (int r = 0; r < 4; ++r) {
        float ma = -1e30f, m1 = -1e30f, m2 = -1e30f, m3 = -1e30f;
#pragma unroll
        for (int cf = 0; cf < 7; ++cf) {
            int colc = wvN * 112 + cf * 16 + l15;
            float v = acc[rf][cf][r];
            if (colc < 350) ma = fmaxf(ma, v);
            else if (colc >= 352 && colc < 362) m1 = fmaxf(m1, v);
            else if (colc >= 362 && colc < 387) m2 = fmaxf(m2, v);
            else if (colc >= 387 && colc < 403) m3 = fmaxf(m3, v);
        }
#pragma unroll
        for (int o = 8; o; o >>= 1) {
            ma = fmaxf(ma, __shfl_xor(ma, o));
            m1 = fmaxf(m1, __shfl_xor(m1, o));
            m2 = fmaxf(m2, __shfl_xor(m2, o));
            m3 = fmaxf(m3, __shfl_xor(m3, o));
        }
        int rowl = wvM * 32 + rf * 16 + lq * 4 + r;
        if (l15 == 0) {
            smx[rowl * 4 + wvN] = ma;
            if (wvN == 3) {
                smx[512 + rowl * 3 + 0] = m1;
                smx[512 + rowl * 3 + 1] = m2;
                smx[512 + rowl * 3 + 2] = m3;
            }
        }
    }
    __syncthreads();
#pragma unroll
    for (int rf = 0; rf < 2; ++rf)
#pragma unroll
    for (int r = 0; r < 4; ++r) {
        int rowl = wvM * 32 + rf * 16 + lq * 4 + r;
        float am = fmaxf(fmaxf(smx[rowl * 4 + 0], smx[rowl * 4 + 1]),
                         fmaxf(smx[rowl * 4 + 2], smx[rowl * 4 + 3]));
        float m1 = 0.f, m2 = 0.f, m3 = 0.f;
        if (wvN == 3) {
            m1 = smx[512 + rowl * 3 + 0];
            m2 = smx[512 + rowl * 3 + 1];
            m3 = smx[512 + rowl * 3 + 2];
        }
        float sa = 0.f, s1 = 0.f, s2 = 0.f, s3 = 0.f;
#pragma unroll
        for (int cf = 0; cf < 7; ++cf) {
            int colc = wvN * 112 + cf * 16 + l15;
            float v = acc[rf][cf][r];
            float e = 0.f;
            if (colc < 350)                     { e = __expf(v - am); sa += e; }
            else if (colc >= 352 && colc < 362) { e = __expf(v - m1); s1 += e; }
            else if (colc >= 362 && colc < 387) { e = __expf(v - m2); s2 += e; }
            else if (colc >= 387 && colc < 403) { e = __expf(v - m3); s3 += e; }
            acc[rf][cf][r] = e;
        }
#pragma unroll
        for (int o = 8; o; o >>= 1) {
            sa += __shfl_xor(sa, o); s1 += __shfl_xor(s1, o);
            s2 += __shfl_xor(s2, o); s3 += __shfl_xor(s3, o);
        }
        if (l15 == 0) {
            smx[256 + rowl * 4 + wvN] = sa;
            if (wvN == 3) {
                smx[704 + rowl * 3 + 0] = s1;
                smx[704 + rowl * 3 + 1] = s2;
                smx[704 + rowl * 3 + 2] = s3;
            }
        }
    }
    __syncthreads();
#pragma unroll
    for (int rf = 0; rf < 2; ++rf)
#pragma unroll
    for (int r = 0; r < 4; ++r) {
        int rowl = wvM * 32 + rf * 16 + lq * 4 + r;
        int row = row0 + rowl;
        if (row >= M) continue;
        float ia = 1.f / (smx[256 + rowl * 4 + 0] + smx[256 + rowl * 4 + 1] +
                          smx[256 + rowl * 4 + 2] + smx[256 + rowl * 4 + 3]);
        float i1 = 0.f, i2 = 0.f, i3 = 0.f;
        if (wvN == 3) {
            i1 = 1.f / smx[704 + rowl * 3 + 0];
            i2 = 1.f / smx[704 + rowl * 3 + 1];
            i3 = 1.f / smx[704 + rowl * 3 + 2];
        }
#pragma unroll
        for (int cf = 0; cf < 7; ++cf) {
            int colc = wvN * 112 + cf * 16 + l15;
            float e = acc[rf][cf][r];
            if (colc < 350)                     o3[(size_t)row * 350 + colc]        = e * ia;
            else if (colc >= 352 && colc < 362) o0[(size_t)row * 10 + (colc - 352)] = e * i1;
            else if (colc >= 362 && colc < 387) o1[(size_t)row * 25 + (colc - 362)] = e * i2;
            else if (colc >= 387 && colc < 403) o2[(size_t)row * 16 + (colc - 387)] = e * i3;
        }
    }
}

// ---------------- launch ----------------
extern "C" void kernel_launch(void* const* d_in, const int* in_sizes, int n_in,
                              void* d_out, int out_size, void* d_ws, size_t ws_size,
                              hipStream_t stream)
{
    const float* x   = (const float*)d_in[0];
    const int*   ei  = (const int*)d_in[1];
    const float* W1  = (const float*)d_in[2];
    const float* b1  = (const float*)d_in[3];
    const float* Wg0 = (const float*)d_in[4];
    const float* bg0 = (const float*)d_in[5];
    const float* Wc0 = (const float*)d_in[6];
    const float* bc0 = (const float*)d_in[7];
    const float* Wg1 = (const float*)d_in[8];
    const float* bg1 = (const float*)d_in[9];
    const float* Wc1 = (const float*)d_in[10];
    const float* bc1 = (const float*)d_in[11];
    const float* Wg2 = (const float*)d_in[12];
    const float* bg2 = (const float*)d_in[13];
    const float* Wc2 = (const float*)d_in[14];
    const float* bc2 = (const float*)d_in[15];
    const float* Wg3 = (const float*)d_in[16];
    const float* bg3 = (const float*)d_in[17];
    const float* Wc3 = (const float*)d_in[18];
    const float* bc3 = (const float*)d_in[19];
    const int* srcI = ei;
    const int* dstI = ei + NE;

    char* ws = (char*)d_ws;
    size_t off = 0;
    auto alloc = [&](size_t bytes) { void* p = ws + off; off += (bytes + 255) & ~(size_t)255; return p; };
    float* dinv   = (float*)alloc(50176 * 4);
    int*   rowptr = (int*)  alloc(50432 * 4);
    int*   cnt    = (int*)  alloc(2 * 50176 * 4);
    int*   cursor = cnt + 50176;
    int*   bsum   = (int*)  alloc(1024);
    int*   bsumx  = (int*)  alloc(1024);
    int*   col    = (int*)  alloc((size_t)NE * 4);
    unsigned short* W1t_sw = (unsigned short*)alloc(256 * 512 * 2);
    unsigned short* Wftp   = (unsigned short*)alloc(448 * 256 * 2);
    float* bfv   = (float*)alloc(448 * 4);
    float* Wg3t  = (float*)alloc(350 * 256 * 4);
    float* Wc3t  = (float*)alloc(350 * 350 * 4);
    unsigned short* xwb = (unsigned short*)alloc((size_t)NN * HIDC * 2);
    unsigned short* hb  = (unsigned short*)alloc((size_t)NN * HIDC * 2);
    unsigned short* ahb = xwb;   // alias: xwb dead after gather1

    float* out0 = (float*)d_out;
    float* out1 = out0 + (size_t)NN * 10;
    float* out2 = out1 + (size_t)NN * 25;
    float* out3 = out2 + (size_t)NN * 16;

    // ---- CSR build ----
    hipMemsetAsync(cnt, 0, 2 * 50176 * 4, stream);
    k_deg_count<<<(NE + 255) / 256, 256, 0, stream>>>(dstI, cnt, NE);
    k_scan1<<<NBLK, 256, 0, stream>>>(cnt, rowptr, bsum, dinv, NN);
    k_scan2<<<1, 256, 0, stream>>>(bsum, bsumx, NBLK);
    k_scan3<<<NBLK, 256, 0, stream>>>(rowptr, bsumx, NN, NE);
    k_fill<<<(NE + 255) / 256, 256, 0, stream>>>(srcI, dstI, rowptr, cursor, col, NE);

    // ---- weight prep ----
    k_tr2<<<(350 * 350 + 255) / 256, 256, 0, stream>>>(Wg3, Wc3, Wg3t, Wc3t);
    k_prep<<<962, 256, 0, stream>>>(W1,
                                    Wg0, Wc0, bg0, bc0, Wg1, Wc1, bg1, bc1,
                                    Wg2, Wc2, bg2, bc2, Wg3, Wc3, bg3, bc3,
                                    Wg3t, Wc3t, W1t_sw, Wftp, bfv);

    // ---- pipeline ----
    gemm1_conv<<<(NN + 63) / 64, 256, 0, stream>>>(x, W1t_sw, xwb, NN);
    k_gather2<true, true><<<(NN + 7) / 8, 256, 0, stream>>>(xwb, rowptr, col, dinv, b1, hb, NN);
    k_gather2<false, false><<<(NN + 7) / 8, 256, 0, stream>>>(hb, rowptr, col, dinv, nullptr, ahb, NN);
    gemm2_heads<<<(NN + 63) / 64, 512, 0, stream>>>(ahb, Wftp, bfv, out0, out1, out2, out3, NN);
}

// Round 8
// 345.251 us; speedup vs baseline: 1.0434x; 1.0434x over previous
//
#include <hip/hip_runtime.h>
#include <hip/hip_bf16.h>
#include <cstdint>
#include <cstddef>
#include <math.h>

#define NN 50000
#define NE 800000
#define INC 512
#define HIDC 256
#define NBLK ((NN + 255) / 256)

typedef __attribute__((ext_vector_type(8))) short s8v;   // 8 bf16 = 4 VGPR
typedef __attribute__((ext_vector_type(4))) float f4v;
typedef unsigned int u32;

#define VMC(n)  asm volatile("s_waitcnt vmcnt(" #n ")" ::: "memory")
#define LGKM0   asm volatile("s_waitcnt lgkmcnt(0)" ::: "memory")
#define SCHED0  __builtin_amdgcn_sched_barrier(0)
#define BAR()   do { __builtin_amdgcn_s_barrier(); asm volatile("" ::: "memory"); } while (0)

__device__ __forceinline__ float b2f(unsigned short u) {
    return __uint_as_float(((unsigned)u) << 16);
}
__device__ __forceinline__ unsigned short f2b(float f) {
    __hip_bfloat16 h = __float2bfloat16(f);
    return *reinterpret_cast<unsigned short*>(&h);
}
// async 16B global->LDS (dest = wave-uniform base, HW adds lane*16; src is per-lane)
__device__ __forceinline__ void gload16(const void* g, void* l) {
    __builtin_amdgcn_global_load_lds(
        (const __attribute__((address_space(1))) u32*)g,
        (__attribute__((address_space(3))) u32*)l, 16, 0, 0);
}

// ---------------- CSR build ----------------
__global__ void k_deg_count(const int* __restrict__ dst, int* __restrict__ cnt, int e) {
    int i = blockIdx.x * 256 + threadIdx.x;
    if (i < e) atomicAdd(&cnt[dst[i]], 1);
}
__global__ void k_scan1(const int* __restrict__ cnt, int* __restrict__ excl,
                        int* __restrict__ bsum, float* __restrict__ dinv, int n) {
    __shared__ int s[256];
    int i = blockIdx.x * 256 + threadIdx.x;
    int v = (i < n) ? cnt[i] : 0;
    if (i < n) dinv[i] = rsqrtf((float)v + 1.0f);
    s[threadIdx.x] = v;
    __syncthreads();
    for (int off = 1; off < 256; off <<= 1) {
        int t = (threadIdx.x >= off) ? s[threadIdx.x - off] : 0;
        __syncthreads();
        s[threadIdx.x] += t;
        __syncthreads();
    }
    if (i < n) excl[i] = s[threadIdx.x] - v;
    if (threadIdx.x == 255) bsum[blockIdx.x] = s[255];
}
__global__ void k_scan2(int* __restrict__ bsum, int* __restrict__ bsumx, int nb) {
    __shared__ int s[256];
    int t = threadIdx.x;
    int v = (t < nb) ? bsum[t] : 0;
    s[t] = v;
    __syncthreads();
    for (int off = 1; off < 256; off <<= 1) {
        int tt = (t >= off) ? s[t - off] : 0;
        __syncthreads();
        s[t] += tt;
        __syncthreads();
    }
    if (t < nb) bsumx[t] = s[t] - v;
}
__global__ void k_scan3(int* __restrict__ rowptr, const int* __restrict__ bsumx, int n, int e) {
    int i = blockIdx.x * 256 + threadIdx.x;
    if (i < n) rowptr[i] += bsumx[blockIdx.x];
    if (i == 0) rowptr[n] = e;
}
__global__ void k_fill(const int* __restrict__ src, const int* __restrict__ dst,
                       const int* __restrict__ rowptr, int* __restrict__ cursor,
                       int* __restrict__ col, int e) {
    int i = blockIdx.x * 256 + threadIdx.x;
    if (i >= e) return;
    int d = dst[i];
    int pos = rowptr[d] + atomicAdd(&cursor[d], 1);
    col[pos] = src[i];
}

// ---------------- transposes for coalesced fold ----------------
__global__ void k_tr2(const float* __restrict__ Wg3, const float* __restrict__ Wc3,
                      float* __restrict__ Wg3t, float* __restrict__ Wc3t) {
    int t = blockIdx.x * 256 + threadIdx.x;
    if (t < 256 * 350) { int k = t / 350, i = t - k * 350; Wg3t[i * 256 + k] = Wg3[t]; }
    if (t < 350 * 350) { int i = t / 350, j = t - i * 350; Wc3t[j * 350 + i] = Wc3[t]; }
}

// ---------------- fused weight prep ----------------
// blocks 0..511: W1t_sw (XOR 8-group, k-blocked) ; 512..959: Wftp col j = b-512
// (plane-major-XOR: chunk ((kb*4+ch)*448 + (j^(ch*2))), elem k&7) ; 960..961: bfv
__global__ void k_prep(const float* __restrict__ W1,
                       const float* __restrict__ Wg0, const float* __restrict__ Wc0,
                       const float* __restrict__ bg0, const float* __restrict__ bc0,
                       const float* __restrict__ Wg1, const float* __restrict__ Wc1,
                       const float* __restrict__ bg1, const float* __restrict__ bc1,
                       const float* __restrict__ Wg2, const float* __restrict__ Wc2,
                       const float* __restrict__ bg2, const float* __restrict__ bc2,
                       const float* __restrict__ Wg3, const float* __restrict__ Wc3,
                       const float* __restrict__ bg3, const float* __restrict__ bc3,
                       const float* __restrict__ Wg3t, const float* __restrict__ Wc3t,
                       unsigned short* __restrict__ W1t_sw, unsigned short* __restrict__ Wftp,
                       float* __restrict__ bfv)
{
    __shared__ float Wcj[352];
    int b = blockIdx.x, tid = threadIdx.x;
    if (b < 512) {
        int t = b * 256 + tid;            // 256*512 elems
        int c = t >> 9, k = t & 511;
        int chs = ((k >> 3) & 7) ^ (c & 7);
        W1t_sw[(size_t)(k >> 6) * 16384 + c * 64 + chs * 8 + (k & 7)] = f2b(W1[(size_t)k * 256 + c]);
    } else if (b < 960) {
        int j = b - 512, k = tid;
        float s = 0.f;
        if (j < 350) {
            for (int i = tid; i < 350; i += 256) Wcj[i] = Wc3t[(size_t)j * 350 + i];
            __syncthreads();
            for (int i = 0; i < 350; ++i) s += Wg3t[i * 256 + k] * Wcj[i];
        } else if (j >= 352 && j < 362) {
            int jj = j - 352; for (int i = 0; i < 10; ++i) s += Wg0[k * 10 + i] * Wc0[i * 10 + jj];
        } else if (j >= 362 && j < 387) {
            int jj = j - 362; for (int i = 0; i < 25; ++i) s += Wg1[k * 25 + i] * Wc1[i * 25 + jj];
        } else if (j >= 387 && j < 403) {
            int jj = j - 387; for (int i = 0; i < 16; ++i) s += Wg2[k * 16 + i] * Wc2[i * 16 + jj];
        }
        int kb = k >> 5, ch = (k >> 3) & 3, e = k & 7;
        Wftp[(((size_t)kb * 4 + ch) * 448 + (j ^ (ch * 2))) * 8 + e] = f2b(s);
    } else {
        int j = (b - 960) * 256 + tid;
        if (j >= 448) return;
        float s = 0.f;
        if (j < 350)                  { s = bc3[j]; for (int i = 0; i < 350; ++i) s += bg3[i] * Wc3[(size_t)i * 350 + j]; }
        else if (j >= 352 && j < 362) { int jj = j - 352; s = bc0[jj]; for (int i = 0; i < 10; ++i) s += bg0[i] * Wc0[i * 10 + jj]; }
        else if (j >= 362 && j < 387) { int jj = j - 362; s = bc1[jj]; for (int i = 0; i < 25; ++i) s += bg1[i] * Wc1[i * 25 + jj]; }
        else if (j >= 387 && j < 403) { int jj = j - 387; s = bc2[jj]; for (int i = 0; i < 16; ++i) s += bg2[i] * Wc2[i * 16 + jj]; }
        bfv[j] = s;
    }
}

// ---------------- gemm1: xwb = bf16( fp32 X[M][512] @ W1 ) ----------------
// BM=64, BN=256, BK=64, 256 thr = 4 waves (2M x 2N), wave-tile 32x128
// double-buffered, counted vmcnt: B via 8 DMAs/wave, A via 4 reg-loads/thread.
__global__ __launch_bounds__(256, 2) void gemm1_conv(
    const float* __restrict__ X, const unsigned short* __restrict__ Bsw,
    unsigned short* __restrict__ C, int M)
{
    __shared__ s8v lds[5120];   // A0 @0 (512) | A1 @512 | B0 @1024 (2048) | B1 @3072
    const int t = threadIdx.x;
    const int lane = t & 63, wv = t >> 6;
    const int wvM = wv >> 1, wvN = wv & 1;
    const int l15 = lane & 15, lq = lane >> 4;
    const int row0 = blockIdx.x * 64;

    const int arow = t >> 2, q = t & 3;
    int gr = row0 + arow; if (gr >= M) gr = M - 1;
    const float* asrc = X + (size_t)gr * INC + q * 16;
    const int awp0 = arow * 8 + ((q * 2) ^ (arow & 7));
    const int awp1 = arow * 8 + ((q * 2 + 1) ^ (arow & 7));

    float4 fa0, fa1, fa2, fa3;
#define STAGE_B1(kbn, buf) do { \
    const unsigned short* bs_ = Bsw + (size_t)(kbn) * 2048 * 8; \
    int bb_ = 1024 + (buf) * 2048; \
    _Pragma("unroll") \
    for (int sB = 0; sB < 8; ++sB) { \
        int g_ = (wv * 8 + sB) * 64; \
        gload16(bs_ + (size_t)(g_ + lane) * 8, (void*)&lds[bb_ + g_]); \
    } } while (0)
#define LOAD_A1(kbn) do { \
    fa0 = *(const float4*)(asrc + (kbn) * 64); \
    fa1 = *(const float4*)(asrc + (kbn) * 64 + 4); \
    fa2 = *(const float4*)(asrc + (kbn) * 64 + 8); \
    fa3 = *(const float4*)(asrc + (kbn) * 64 + 12); } while (0)

    f4v acc[2][8] = {};
    STAGE_B1(0, 0);
    LOAD_A1(0);
    for (int kb = 0; kb < 8; ++kb) {
        const int cur = kb & 1, nxt = cur ^ 1;
        if (kb < 7) STAGE_B1(kb + 1, nxt);
        if (kb < 7) { VMC(8); } else { VMC(0); }
        // convert A(kb) regs -> ds_write into bufA[cur]
        s8v o0, o1;
        o0[0]=(short)f2b(fa0.x); o0[1]=(short)f2b(fa0.y); o0[2]=(short)f2b(fa0.z); o0[3]=(short)f2b(fa0.w);
        o0[4]=(short)f2b(fa1.x); o0[5]=(short)f2b(fa1.y); o0[6]=(short)f2b(fa1.z); o0[7]=(short)f2b(fa1.w);
        o1[0]=(short)f2b(fa2.x); o1[1]=(short)f2b(fa2.y); o1[2]=(short)f2b(fa2.z); o1[3]=(short)f2b(fa2.w);
        o1[4]=(short)f2b(fa3.x); o1[5]=(short)f2b(fa3.y); o1[6]=(short)f2b(fa3.z); o1[7]=(short)f2b(fa3.w);
        lds[cur * 512 + awp0] = o0;
        lds[cur * 512 + awp1] = o1;
        if (kb < 7) LOAD_A1(kb + 1);
        LGKM0; BAR();
        const int ab = cur * 512, bb = 1024 + cur * 2048;
        __builtin_amdgcn_s_setprio(1);
#pragma unroll
        for (int kk = 0; kk < 2; ++kk) {
            const int chr = (kk * 4 + lq) ^ (l15 & 7);
            s8v a0 = lds[ab + (wvM * 32 + l15) * 8 + chr];
            s8v a1 = lds[ab + (wvM * 32 + 16 + l15) * 8 + chr];
#pragma unroll
            for (int cf = 0; cf < 8; ++cf) {
                s8v bf = lds[bb + (wvN * 128 + cf * 16 + l15) * 8 + chr];
                acc[0][cf] = __builtin_amdgcn_mfma_f32_16x16x32_bf16(a0, bf, acc[0][cf], 0, 0, 0);
                acc[1][cf] = __builtin_amdgcn_mfma_f32_16x16x32_bf16(a1, bf, acc[1][cf], 0, 0, 0);
            }
        }
        __builtin_amdgcn_s_setprio(0);
        LGKM0; BAR();
    }
#pragma unroll
    for (int rf = 0; rf < 2; ++rf)
#pragma unroll
    for (int r = 0; r < 4; ++r) {
        int row = row0 + wvM * 32 + rf * 16 + lq * 4 + r;
        if (row >= M) continue;
#pragma unroll
        for (int cf = 0; cf < 8; ++cf)
            C[(size_t)row * HIDC + wvN * 128 + cf * 16 + l15] = f2b(acc[rf][cf][r]);
    }
#undef STAGE_B1
#undef LOAD_A1
}

// ---------------- gather: 2 nodes/wave, 32 lanes x ushort8 per row ----------------
template <bool RELU, bool BIAS>
__global__ __launch_bounds__(256) void k_gather2(
    const unsigned short* __restrict__ feat, const int* __restrict__ rowptr,
    const int* __restrict__ col, const float* __restrict__ dinv,
    const float* __restrict__ bias, unsigned short* __restrict__ out, int n)
{
    int unit = (blockIdx.x * 256 + threadIdx.x) >> 5;
    int l32 = threadIdx.x & 31;
    if (unit >= n) return;
    float di = dinv[unit];
    int p0 = rowptr[unit], p1 = rowptr[unit + 1];
    int deg = p1 - p0;
    int myc = 0; float mydj = 0.f;
    if (l32 < deg) { myc = col[p0 + l32]; mydj = dinv[myc]; }
    float acc[8] = {};
    int dmin = deg < 32 ? deg : 32;
    int base = threadIdx.x & 32;
#pragma unroll 2
    for (int q = 0; q < dmin; ++q) {
        int j = __shfl(myc, base + q);
        float dj = __shfl(mydj, base + q);
        s8v v = *(const s8v*)(feat + (size_t)j * HIDC + l32 * 8);
#pragma unroll
        for (int c = 0; c < 8; ++c) acc[c] += dj * b2f((unsigned short)v[c]);
    }
    for (int p = p0 + 32; p < p1; ++p) {
        int j = col[p];
        float dj = dinv[j];
        s8v v = *(const s8v*)(feat + (size_t)j * HIDC + l32 * 8);
#pragma unroll
        for (int c = 0; c < 8; ++c) acc[c] += dj * b2f((unsigned short)v[c]);
    }
    s8v sv = *(const s8v*)(feat + (size_t)unit * HIDC + l32 * 8);
    float dd = di * di;
    s8v o;
#pragma unroll
    for (int c = 0; c < 8; ++c) {
        float r = di * acc[c] + dd * b2f((unsigned short)sv[c]);
        if (BIAS) r += bias[l32 * 8 + c];
        if (RELU) r = fmaxf(r, 0.f);
        o[c] = (short)f2b(r);
    }
    *(s8v*)(out + (size_t)unit * HIDC + l32 * 8) = o;
}

// ---------------- gemm2 + 4-head softmax ----------------
// BM=64, BN=448, BK=32, 512 thr = 8 waves (2M x 4N), wave-tile 32x112
// k-slot-plane-major LDS (conflict-free): chunk = plane*ncols + (col ^ (plane*2)).
// double-buffered A(4KB)+B(28KB) x2 = 64KB -> 2 blocks/CU; vmcnt(4)/wave/k-step.
__global__ __launch_bounds__(512, 4) void gemm2_heads(
    const unsigned short* __restrict__ Ap, const unsigned short* __restrict__ Bp,
    const float* __restrict__ bfv,
    float* __restrict__ o0, float* __restrict__ o1,
    float* __restrict__ o2, float* __restrict__ o3, int M)
{
    __shared__ s8v lds[4096];   // A0 @0 (256) | A1 @256 | B0 @512 (1792) | B1 @2304
    const int t = threadIdx.x;
    const int lane = t & 63, wv = t >> 6;
    const int wvM = wv >> 2, wvN = wv & 3;
    const int l15 = lane & 15, lq = lane >> 4;
    const int row0 = blockIdx.x * 64;

#define STAGE2(kbn, buf) do { \
    if (wv == 0) { \
        _Pragma("unroll") \
        for (int s = 0; s < 4; ++s) { \
            int grow_ = row0 + (lane ^ (s * 2)); if (grow_ >= M) grow_ = M - 1; \
            gload16(Ap + (size_t)grow_ * HIDC + (kbn) * 32 + s * 8, \
                    (void*)&lds[(buf) * 256 + s * 64]); \
        } \
    } else { \
        _Pragma("unroll") \
        for (int s = 0; s < 4; ++s) { \
            int bg_ = (wv - 1) * 4 + s; \
            gload16(Bp + ((size_t)(kbn) * 1792 + bg_ * 64 + lane) * 8, \
                    (void*)&lds[512 + (buf) * 1792 + bg_ * 64]); \
        } \
    } } while (0)

    f4v acc[2][7] = {};
    STAGE2(0, 0);
    for (int kb = 0; kb < 8; ++kb) {
        const int cur = kb & 1, nxt = cur ^ 1;
        if (kb < 7) STAGE2(kb + 1, nxt);
        if (kb < 7) { VMC(4); } else { VMC(0); }
        BAR();                       // buf[cur] fully staged across all waves
        const int ab = cur * 256, bb = 512 + cur * 1792;
        const int l15x = l15 ^ (lq * 2);
        s8v a0 = lds[ab + lq * 64 + wvM * 32 + l15x];
        s8v a1 = lds[ab + lq * 64 + wvM * 32 + 16 + l15x];
        s8v bfr[7];
#pragma unroll
        for (int cf = 0; cf < 7; ++cf)
            bfr[cf] = lds[bb + lq * 448 + wvN * 112 + cf * 16 + l15x];
        LGKM0; SCHED0;
        BAR();                       // reads done -> next STAGE may overwrite cur
        __builtin_amdgcn_s_setprio(1);
#pragma unroll
        for (int cf = 0; cf < 7; ++cf) {
            acc[0][cf] = __builtin_amdgcn_mfma_f32_16x16x32_bf16(a0, bfr[cf], acc[0][cf], 0, 0, 0);
            acc[1][cf] = __builtin_amdgcn_mfma_f32_16x16x32_bf16(a1, bfr[cf], acc[1][cf], 0, 0, 0);
        }
        __builtin_amdgcn_s_setprio(0);
    }
#undef STAGE2
    // ---- epilogue: bias + 4-head segmented softmax ----
    float* smx = (float*)lds;   // reuse A0 region only: amax[64][4]@0, asum@256, hmax@512, hsum@704
#pragma unroll
    for (int cf = 0; cf < 7; ++cf) {
        float bb = bfv[wvN * 112 + cf * 16 + l15];
#pragma unroll
        for (int rf = 0; rf < 2; ++rf)
#pragma unroll
        for (int r = 0; r < 4; ++r) acc[rf][cf][r] += bb;
    }
#pragma unroll
    for (int rf = 0; rf < 2; ++rf)
#pragma unroll
    for (int r = 0; r < 4; ++r) {
        float ma = -1e30f, m1 = -1e30f, m2 = -1e30f, m3 = -1e30f;
#pragma unroll
        for (int cf = 0; cf < 7; ++cf) {
            int colc = wvN * 112 + cf * 16 + l15;
            float v = acc[rf][cf][r];
            if (colc < 350) ma = fmaxf(ma, v);
            else if (colc >= 352 && colc < 362) m1 = fmaxf(m1, v);
            else if (colc >= 362 && colc < 387) m2 = fmaxf(m2, v);
            else if (colc >= 387 && colc < 403) m3 = fmaxf(m3, v);
        }
#pragma unroll
        for (int o = 8; o; o >>= 1) {
            ma = fmaxf(ma, __shfl_xor(ma, o));
            m1 = fmaxf(m1, __shfl_xor(m1, o));
            m2 = fmaxf(m2, __shfl_xor(m2, o));
            m3 = fmaxf(m3, __shfl_xor(m3, o));
        }
        int rowl = wvM * 32 + rf * 16 + lq * 4 + r;
        if (l15 == 0) {
            smx[rowl * 4 + wvN] = ma;
            if (wvN == 3) {
                smx[512 + rowl * 3 + 0] = m1;
                smx[512 + rowl * 3 + 1] = m2;
                smx[512 + rowl * 3 + 2] = m3;
            }
        }
    }
    __syncthreads();
#pragma unroll
    for (int rf = 0; rf < 2; ++rf)
#pragma unroll
    for (int r = 0; r < 4; ++r) {
        int rowl = wvM * 32 + rf * 16 + lq * 4 + r;
        float am = fmaxf(fmaxf(smx[rowl * 4 + 0], smx[rowl * 4 + 1]),
                         fmaxf(smx[rowl * 4 + 2], smx[rowl * 4 + 3]));
        float m1 = 0.f, m2 = 0.f, m3 = 0.f;
        if (wvN == 3) {
            m1 = smx[512 + rowl * 3 + 0];
            m2 = smx[512 + rowl * 3 + 1];
            m3 = smx[512 + rowl * 3 + 2];
        }
        float sa = 0.f, s1 = 0.f, s2 = 0.f, s3 = 0.f;
#pragma unroll
        for (int cf = 0; cf < 7; ++cf) {
            int colc = wvN * 112 + cf * 16 + l15;
            float v = acc[rf][cf][r];
            float e = 0.f;
            if (colc < 350)                     { e = __expf(v - am); sa += e; }
            else if (colc >= 352 && colc < 362) { e = __expf(v - m1); s1 += e; }
            else if (colc >= 362 && colc < 387) { e = __expf(v - m2); s2 += e; }
            else if (colc >= 387 && colc < 403) { e = __expf(v - m3); s3 += e; }
            acc[rf][cf][r] = e;
        }
#pragma unroll
        for (int o = 8; o; o >>= 1) {
            sa += __shfl_xor(sa, o); s1 += __shfl_xor(s1, o);
            s2 += __shfl_xor(s2, o); s3 += __shfl_xor(s3, o);
        }
        if (l15 == 0) {
            smx[256 + rowl * 4 + wvN] = sa;
            if (wvN == 3) {
                smx[704 + rowl * 3 + 0] = s1;
                smx[704 + rowl * 3 + 1] = s2;
                smx[704 + rowl * 3 + 2] = s3;
            }
        }
    }
    __syncthreads();
#pragma unroll
    for (int rf = 0; rf < 2; ++rf)
#pragma unroll
    for (int r = 0; r < 4; ++r) {
        int rowl = wvM * 32 + rf * 16 + lq * 4 + r;
        int row = row0 + rowl;
        if (row >= M) continue;
        float ia = 1.f / (smx[256 + rowl * 4 + 0] + smx[256 + rowl * 4 + 1] +
                          smx[256 + rowl * 4 + 2] + smx[256 + rowl * 4 + 3]);
        float i1 = 0.f, i2 = 0.f, i3 = 0.f;
        if (wvN == 3) {
            i1 = 1.f / smx[704 + rowl * 3 + 0];
            i2 = 1.f / smx[704 + rowl * 3 + 1];
            i3 = 1.f / smx[704 + rowl * 3 + 2];
        }
#pragma unroll
        for (int cf = 0; cf < 7; ++cf) {
            int colc = wvN * 112 + cf * 16 + l15;
            float e = acc[rf][cf][r];
            if (colc < 350)                     o3[(size_t)row * 350 + colc]        = e * ia;
            else if (colc >= 352 && colc < 362) o0[(size_t)row * 10 + (colc - 352)] = e * i1;
            else if (colc >= 362 && colc < 387) o1[(size_t)row * 25 + (colc - 362)] = e * i2;
            else if (colc >= 387 && colc < 403) o2[(size_t)row * 16 + (colc - 387)] = e * i3;
        }
    }
}

// ---------------- launch ----------------
extern "C" void kernel_launch(void* const* d_in, const int* in_sizes, int n_in,
                              void* d_out, int out_size, void* d_ws, size_t ws_size,
                              hipStream_t stream)
{
    const float* x   = (const float*)d_in[0];
    const int*   ei  = (const int*)d_in[1];
    const float* W1  = (const float*)d_in[2];
    const float* b1  = (const float*)d_in[3];
    const float* Wg0 = (const float*)d_in[4];
    const float* bg0 = (const float*)d_in[5];
    const float* Wc0 = (const float*)d_in[6];
    const float* bc0 = (const float*)d_in[7];
    const float* Wg1 = (const float*)d_in[8];
    const float* bg1 = (const float*)d_in[9];
    const float* Wc1 = (const float*)d_in[10];
    const float* bc1 = (const float*)d_in[11];
    const float* Wg2 = (const float*)d_in[12];
    const float* bg2 = (const float*)d_in[13];
    const float* Wc2 = (const float*)d_in[14];
    const float* bc2 = (const float*)d_in[15];
    const float* Wg3 = (const float*)d_in[16];
    const float* bg3 = (const float*)d_in[17];
    const float* Wc3 = (const float*)d_in[18];
    const float* bc3 = (const float*)d_in[19];
    const int* srcI = ei;
    const int* dstI = ei + NE;

    char* ws = (char*)d_ws;
    size_t off = 0;
    auto alloc = [&](size_t bytes) { void* p = ws + off; off += (bytes + 255) & ~(size_t)255; return p; };
    float* dinv   = (float*)alloc(50176 * 4);
    int*   rowptr = (int*)  alloc(50432 * 4);
    int*   cnt    = (int*)  alloc(2 * 50176 * 4);
    int*   cursor = cnt + 50176;
    int*   bsum   = (int*)  alloc(1024);
    int*   bsumx  = (int*)  alloc(1024);
    int*   col    = (int*)  alloc((size_t)NE * 4);
    unsigned short* W1t_sw = (unsigned short*)alloc(256 * 512 * 2);
    unsigned short* Wftp   = (unsigned short*)alloc(448 * 256 * 2);
    float* bfv   = (float*)alloc(448 * 4);
    float* Wg3t  = (float*)alloc(350 * 256 * 4);
    float* Wc3t  = (float*)alloc(350 * 350 * 4);
    unsigned short* xwb = (unsigned short*)alloc((size_t)NN * HIDC * 2);
    unsigned short* hb  = (unsigned short*)alloc((size_t)NN * HIDC * 2);
    unsigned short* ahb = xwb;   // alias: xwb dead after gather1

    float* out0 = (float*)d_out;
    float* out1 = out0 + (size_t)NN * 10;
    float* out2 = out1 + (size_t)NN * 25;
    float* out3 = out2 + (size_t)NN * 16;

    // ---- CSR build ----
    hipMemsetAsync(cnt, 0, 2 * 50176 * 4, stream);
    k_deg_count<<<(NE + 255) / 256, 256, 0, stream>>>(dstI, cnt, NE);
    k_scan1<<<NBLK, 256, 0, stream>>>(cnt, rowptr, bsum, dinv, NN);
    k_scan2<<<1, 256, 0, stream>>>(bsum, bsumx, NBLK);
    k_scan3<<<NBLK, 256, 0, stream>>>(rowptr, bsumx, NN, NE);
    k_fill<<<(NE + 255) / 256, 256, 0, stream>>>(srcI, dstI, rowptr, cursor, col, NE);

    // ---- weight prep ----
    k_tr2<<<(350 * 350 + 255) / 256, 256, 0, stream>>>(Wg3, Wc3, Wg3t, Wc3t);
    k_prep<<<962, 256, 0, stream>>>(W1,
                                    Wg0, Wc0, bg0, bc0, Wg1, Wc1, bg1, bc1,
                                    Wg2, Wc2, bg2, bc2, Wg3, Wc3, bg3, bc3,
                                    Wg3t, Wc3t, W1t_sw, Wftp, bfv);

    // ---- pipeline ----
    gemm1_conv<<<(NN + 63) / 64, 256, 0, stream>>>(x, W1t_sw, xwb, NN);
    k_gather2<true, true><<<(NN + 7) / 8, 256, 0, stream>>>(xwb, rowptr, col, dinv, b1, hb, NN);
    k_gather2<false, false><<<(NN + 7) / 8, 256, 0, stream>>>(hb, rowptr, col, dinv, nullptr, ahb, NN);
    gemm2_heads<<<(NN + 63) / 64, 512, 0, stream>>>(ahb, Wftp, bfv, out0, out1, out2, out3, NN);
}